// Round 15
// baseline (162.129 us; speedup 1.0000x reference)
//
#include <hip/hip_runtime.h>
#include <cstdint>
#include <cstddef>

#define S_LEN 2048
#define NHEAD 16
#define HDIM  64
#define HID_  1024

typedef short s8v  __attribute__((ext_vector_type(8)));
typedef short s4v  __attribute__((ext_vector_type(4)));
typedef float f4v  __attribute__((ext_vector_type(4)));
typedef float f16v __attribute__((ext_vector_type(16)));

__device__ __forceinline__ short f2b(float x) {
    union { float f; unsigned u; } a; a.f = x;
    unsigned r = a.u + 0x7fffu + ((a.u >> 16) & 1u);
    return (short)(r >> 16);
}
__device__ __forceinline__ float b2f(short x) {
    union { unsigned u; float f; } a; a.u = ((unsigned)(unsigned short)x) << 16;
    return a.f;
}

__device__ __forceinline__ unsigned cvtpk(float a, float b) {
    unsigned r;
    asm("v_cvt_pk_bf16_f32 %0, %1, %2" : "=v"(r) : "v"(a), "v"(b));
    return r;
}
__device__ __forceinline__ void plswap(unsigned& a, unsigned& b) {
    asm("v_permlane32_swap_b32 %0, %1" : "+v"(a), "+v"(b));
}

// ---------------- merged prep: X->bf16, weights->bf16, RoPE table --------------
__global__ __launch_bounds__(256) void prep_kernel(
    const float* __restrict__ X,
    const float* __restrict__ Wq, const float* __restrict__ Wk,
    const float* __restrict__ Wv, const float* __restrict__ Wo,
    short* __restrict__ Xb, short* __restrict__ Wcat, short* __restrict__ Wob,
    float2* __restrict__ rtab)
{
    const int bid = blockIdx.x;
    if (bid < 4096) {
        const float* src;
        short* dst;
        int i;
        if (bid < 2048) {
            src = X; dst = Xb; i = (bid * 256 + threadIdx.x) * 2;
        } else {
            int w = (bid - 2048) >> 9;             // 0..3
            src = (w == 0) ? Wq : (w == 1) ? Wk : (w == 2) ? Wv : Wo;
            dst = (w < 3) ? (Wcat + (size_t)w * 1048576) : Wob;
            i = (((bid - 2048) & 511) * 256 + threadIdx.x) * 2;
        }
        float4 v0 = reinterpret_cast<const float4*>(src)[i];
        float4 v1 = reinterpret_cast<const float4*>(src)[i + 1];
        s8v o;
        o[0] = f2b(v0.x); o[1] = f2b(v0.y); o[2] = f2b(v0.z); o[3] = f2b(v0.w);
        o[4] = f2b(v1.x); o[5] = f2b(v1.y); o[6] = f2b(v1.z); o[7] = f2b(v1.w);
        *reinterpret_cast<s8v*>(&dst[i * 4]) = o;
    } else {
        int idx = (bid - 4096) * 256 + threadIdx.x;   // 65536
        int s = idx >> 5, j = idx & 31;
        float inv = exp2f(-0.5f * (float)j);          // 65536^(-2j/64)
        float ang = (float)s * inv;
        float2 cs; cs.x = cosf(ang); cs.y = sinf(ang);
        rtab[idx] = cs;
    }
}

// ---------------- fused QKV GEMM: 2x16KB buffers, reg-staged, ONE barrier/step -
__global__ __launch_bounds__(256, 4) void gemm_qkv(
    const short* __restrict__ A, const short* __restrict__ Bw,
    const float* __restrict__ bq, const float* __restrict__ bk,
    const float* __restrict__ bv,
    short* __restrict__ Qo, short* __restrict__ Ko, short* __restrict__ Vo,
    const float2* __restrict__ rtab)
{
    __shared__ short Asl[2][4096];   // 128x32 bf16 (8KB) x2
    __shared__ short Bsl[2][4096];
    const int t = threadIdx.x;
    const int lane = t & 63;
    const int l15 = lane & 15, l4 = lane >> 4;
    const int wid = t >> 6;
    const int blk = blockIdx.x;
    const int x = blk & 7, j = blk >> 3;       // j in [0,96)
    const int tn = (x * 3 + j % 3) * 128;
    const int tm = (j / 3) * 128;
    const int K = 1024;
    const int wrow = (wid >> 1) * 64, wcol = (wid & 1) * 64;

    f4v acc[4][4];
#pragma unroll
    for (int i = 0; i < 4; ++i)
#pragma unroll
        for (int jj = 0; jj < 4; ++jj) acc[i][jj] = (f4v){0.f, 0.f, 0.f, 0.f};

    const int r0 = t >> 2;            // staging row within 64-row half
    const int c0 = (t & 3) * 8;       // k-col (8 bf16)

    const short* Ap0 = A  + (size_t)(tm + r0)      * K + c0;
    const short* Ap1 = A  + (size_t)(tm + 64 + r0) * K + c0;
    const short* Bp0 = Bw + (size_t)(tn + r0)      * K + c0;
    const short* Bp1 = Bw + (size_t)(tn + 64 + r0) * K + c0;
    const int wofs = t * 8;

    {   // prologue: tile 0 -> buf 0
        s8v ga0 = *(const s8v*)(Ap0);
        s8v ga1 = *(const s8v*)(Ap1);
        s8v gb0 = *(const s8v*)(Bp0);
        s8v gb1 = *(const s8v*)(Bp1);
        *(s8v*)&Asl[0][wofs] = ga0; *(s8v*)&Asl[0][2048 + wofs] = ga1;
        *(s8v*)&Bsl[0][wofs] = gb0; *(s8v*)&Bsl[0][2048 + wofs] = gb1;
    }
    __syncthreads();

    int cur = 0;
    for (int kt = 0; kt < 32; ++kt) {
        s8v ga0, ga1, gb0, gb1;
        const bool pre = (kt < 31);
        if (pre) {   // T14 issue-early
            const int k0 = (kt + 1) << 5;
            ga0 = *(const s8v*)(Ap0 + k0);
            ga1 = *(const s8v*)(Ap1 + k0);
            gb0 = *(const s8v*)(Bp0 + k0);
            gb1 = *(const s8v*)(Bp1 + k0);
        }
        s8v af[4], bf[4];
#pragma unroll
        for (int i = 0; i < 4; ++i) {
            af[i] = *(const s8v*)&Asl[cur][(wrow + i * 16 + l15) * 32 + 8 * l4];
            bf[i] = *(const s8v*)&Bsl[cur][(wcol + i * 16 + l15) * 32 + 8 * l4];
        }
#pragma unroll
        for (int i = 0; i < 4; ++i)
#pragma unroll
            for (int jj = 0; jj < 4; ++jj)
                acc[i][jj] = __builtin_amdgcn_mfma_f32_16x16x32_bf16(af[i], bf[jj], acc[i][jj], 0, 0, 0);
        if (pre) {   // write-late into the OTHER buffer
            *(s8v*)&Asl[cur ^ 1][wofs] = ga0; *(s8v*)&Asl[cur ^ 1][2048 + wofs] = ga1;
            *(s8v*)&Bsl[cur ^ 1][wofs] = gb0; *(s8v*)&Bsl[cur ^ 1][2048 + wofs] = gb1;
        }
        __syncthreads();             // ONE barrier per K-step
        cur ^= 1;
    }

    const int mode = tn >> 10;                         // 0=Q 1=K 2=V
    const float* bias = (mode == 0) ? bq : (mode == 1) ? bk : bv;
    short* outb = (mode == 0) ? Qo : (mode == 1) ? Ko : Vo;

    if (mode == 2) {   // V: write transposed [bh][d][s]
#pragma unroll
        for (int i = 0; i < 4; ++i) {
            int rowb = tm + wrow + i * 16 + l4 * 4;
            int b_ = rowb >> 11, s0 = rowb & 2047;
#pragma unroll
            for (int jj = 0; jj < 4; ++jj) {
                int col = tn + wcol + jj * 16 + l15;
                int cm = col & 1023;
                float bvv = bias[cm];
                int h = cm >> 6, d = col & 63;
                s4v o4;
#pragma unroll
                for (int r = 0; r < 4; ++r) o4[r] = f2b(acc[i][jj][r] + bvv);
                *(s4v*)&outb[((size_t)((b_ * NHEAD + h) * 64 + d)) * S_LEN + s0] = o4;
            }
        }
    } else {           // Q or K: RoPE. Wave spans exactly one head (64 cols).
        int h = ((tn & 1023) + wcol) >> 6;
        const float osc = (mode == 0) ? 0.180336880111f : 1.0f;  // 1/8 * log2(e)
#pragma unroll
        for (int i = 0; i < 4; ++i) {
#pragma unroll
            for (int r = 0; r < 4; ++r) {
                int row = tm + wrow + i * 16 + l4 * 4 + r;
                int b_ = row >> 11, s = row & 2047;
                float2 cs0 = rtab[(s << 5) + l15];
                float2 cs1 = rtab[(s << 5) + 16 + l15];
#pragma unroll
                for (int jj = 0; jj < 4; ++jj) {
                    int col = tn + wcol + jj * 16 + l15;
                    int cm = col & 1023;
                    int d = col & 63;
                    float v  = acc[i][jj][r]     + bias[cm];
                    float vp = acc[i][jj ^ 2][r] + bias[cm ^ 32];
                    float2 cs = (jj & 1) ? cs1 : cs0;
                    float res = (d < 32) ? (v * cs.x - vp * cs.y)
                                         : (v * cs.x + vp * cs.y);
                    outb[(((size_t)(b_ * NHEAD + h) * S_LEN + s) << 6) + d] = f2b(res * osc);
                }
            }
        }
    }
}

// ---------------- O-proj GEMM: BM=64, 2-buf reg-staged, ONE barrier/step -------
__global__ __launch_bounds__(256, 4) void gemm_o(
    const short* __restrict__ A, const short* __restrict__ Bw,
    const float* __restrict__ bias, float* __restrict__ outf)
{
    __shared__ short Asl[2][2048];   // 64x32 (4KB) x2
    __shared__ short Bsl[2][4096];   // 128x32 (8KB) x2
    const int t = threadIdx.x;
    const int lane = t & 63;
    const int l15 = lane & 15, l4 = lane >> 4;
    const int wid = t >> 6;
    const int blk = blockIdx.x;                 // 512
    const int tn = (blk & 7) * 128;
    const int tm = (blk >> 3) * 64;
    const int K = 1024, N = 1024;
    const int wrow = (wid >> 1) * 32, wcol = (wid & 1) * 64;

    f4v acc[2][4];
#pragma unroll
    for (int i = 0; i < 2; ++i)
#pragma unroll
        for (int jj = 0; jj < 4; ++jj) acc[i][jj] = (f4v){0.f, 0.f, 0.f, 0.f};

    const int r0 = t >> 2;
    const int c0 = (t & 3) * 8;
    const short* Ap0 = A  + (size_t)(tm + r0)      * K + c0;
    const short* Bp0 = Bw + (size_t)(tn + r0)      * K + c0;
    const short* Bp1 = Bw + (size_t)(tn + 64 + r0) * K + c0;
    const int wofs = t * 8;

    {   // prologue
        s8v ga0 = *(const s8v*)(Ap0);
        s8v gb0 = *(const s8v*)(Bp0);
        s8v gb1 = *(const s8v*)(Bp1);
        *(s8v*)&Asl[0][wofs] = ga0;
        *(s8v*)&Bsl[0][wofs] = gb0; *(s8v*)&Bsl[0][2048 + wofs] = gb1;
    }
    __syncthreads();

    int cur = 0;
    for (int kt = 0; kt < 32; ++kt) {
        s8v ga0, gb0, gb1;
        const bool pre = (kt < 31);
        if (pre) {
            const int k0 = (kt + 1) << 5;
            ga0 = *(const s8v*)(Ap0 + k0);
            gb0 = *(const s8v*)(Bp0 + k0);
            gb1 = *(const s8v*)(Bp1 + k0);
        }
        s8v af[2], bf[4];
#pragma unroll
        for (int i = 0; i < 2; ++i)
            af[i] = *(const s8v*)&Asl[cur][(wrow + i * 16 + l15) * 32 + 8 * l4];
#pragma unroll
        for (int jj = 0; jj < 4; ++jj)
            bf[jj] = *(const s8v*)&Bsl[cur][(wcol + jj * 16 + l15) * 32 + 8 * l4];
#pragma unroll
        for (int i = 0; i < 2; ++i)
#pragma unroll
            for (int jj = 0; jj < 4; ++jj)
                acc[i][jj] = __builtin_amdgcn_mfma_f32_16x16x32_bf16(af[i], bf[jj], acc[i][jj], 0, 0, 0);
        if (pre) {
            *(s8v*)&Asl[cur ^ 1][wofs] = ga0;
            *(s8v*)&Bsl[cur ^ 1][wofs] = gb0; *(s8v*)&Bsl[cur ^ 1][2048 + wofs] = gb1;
        }
        __syncthreads();             // ONE barrier per K-step
        cur ^= 1;
    }

#pragma unroll
    for (int i = 0; i < 2; ++i) {
        int rowb = tm + wrow + i * 16 + l4 * 4;
#pragma unroll
        for (int jj = 0; jj < 4; ++jj) {
            int col = tn + wcol + jj * 16 + l15;
            float bv = bias[col];
#pragma unroll
            for (int r = 0; r < 4; ++r)
                outf[(size_t)(rowb + r) * N + col] = acc[i][jj][r] + bv;
        }
    }
}

// ---------------- attention, split-KV, 2x16KB dbuf, ONE barrier/tile -----------
// Row-sum via MFMA with ones-A (moves softmax denominator off the VALU pipe).
#define SWB(row, bofs) ((bofs) ^ (((row) & 7) << 4))

__global__ __launch_bounds__(256, 4) void attn_split(
    const short* __restrict__ Q, const short* __restrict__ K,
    const short* __restrict__ Vt,
    short* __restrict__ P0, short* __restrict__ P1, float2* __restrict__ ML)
{
    __shared__ short Kl[2][4096];   // [key][d] 64x64, swizzled rows (8KB each)
    __shared__ short Vl[2][4096];   // [d][key] 64x64, swizzled rows

    const int t = threadIdx.x, lane = t & 63;
    const int wid = t >> 6;
    const int q5 = lane & 31, hi = lane >> 5;

    const int blk = blockIdx.x;
    const int x = blk & 7, j = blk >> 3;       // j in [0,128)
    const int bh = x * 4 + (j & 3);
    const int rest = j >> 2;                   // 0..31
    const int qb = rest & 15, split = rest >> 4;
    const int kt0 = split * 16;

    const short* Qb = Q + (size_t)bh * S_LEN * 64;
    const char*  Kb = (const char*)(K  + (size_t)bh * S_LEN * 64);
    const char*  Vb = (const char*)(Vt + (size_t)bh * S_LEN * 64);
    const int qrow = qb * 128 + wid * 32 + q5;

    s8v qf[4];
#pragma unroll
    for (int sl = 0; sl < 4; ++sl)
        qf[sl] = *(const s8v*)&Qb[(size_t)qrow * 64 + sl * 16 + hi * 8];

    f16v oacc[2];
#pragma unroll
    for (int dt = 0; dt < 2; ++dt)
#pragma unroll
        for (int e = 0; e < 16; ++e) oacc[dt][e] = 0.f;
    f16v sumacc;                       // denominator accumulator (MFMA ones-row)
#pragma unroll
    for (int e = 0; e < 16; ++e) sumacc[e] = 0.f;
    float m2 = -1e30f;
    s8v ones8;
#pragma unroll
    for (int e = 0; e < 8; ++e) ones8[e] = (short)0x3F80;   // bf16 1.0

    const int skey  = t >> 3;                  // 0..31
    const int sboff = (t & 7) * 16;
    const int sw    = SWB(skey, sboff);
    const size_t kgoff = (size_t)skey * 128  + sboff;
    const size_t vgoff = (size_t)skey * 4096 + sboff;
    const int w0 = skey * 128 + sw;
    const int w1 = w0 + 32 * 128;

    {   // prologue: tile kt0 -> buf 0
        const size_t kbB = (size_t)kt0 * 64 * 128;
        const size_t vbB = (size_t)kt0 * 64 * 2;
        s8v g0 = *(const s8v*)(Kb + kbB + kgoff);
        s8v g1 = *(const s8v*)(Kb + kbB + kgoff + 32 * 128);
        s8v g2 = *(const s8v*)(Vb + vbB + vgoff);
        s8v g3 = *(const s8v*)(Vb + vbB + vgoff + 32 * 4096);
        *(s8v*)((char*)Kl[0] + w0) = g0; *(s8v*)((char*)Kl[0] + w1) = g1;
        *(s8v*)((char*)Vl[0] + w0) = g2; *(s8v*)((char*)Vl[0] + w1) = g3;
    }
    __syncthreads();

    int cur = 0;
    for (int kt = kt0; kt < kt0 + 16; ++kt) {
        s8v g0, g1, g2, g3;
        const bool pre = (kt < kt0 + 15);
        if (pre) {
            const size_t kbB = (size_t)(kt + 1) * 64 * 128;
            const size_t vbB = (size_t)(kt + 1) * 64 * 2;
            g0 = *(const s8v*)(Kb + kbB + kgoff);
            g1 = *(const s8v*)(Kb + kbB + kgoff + 32 * 128);
            g2 = *(const s8v*)(Vb + vbB + vgoff);
            g3 = *(const s8v*)(Vb + vbB + vgoff + 32 * 4096);
        }
        const char* KlB = (const char*)Kl[cur];
        const char* VlB = (const char*)Vl[cur];

        // ---- QK^T (swapped), interleaved c-chains ----
        f16v sc[2];
#pragma unroll
        for (int e = 0; e < 16; ++e) { sc[0][e] = 0.f; sc[1][e] = 0.f; }
        {
            const int kr0 = q5, kr1 = 32 + q5;
            const char* kb0 = KlB + kr0 * 128;
            const char* kb1 = KlB + kr1 * 128;
            __builtin_amdgcn_s_setprio(1);
#pragma unroll
            for (int sl = 0; sl < 4; ++sl) {
                s8v kf0 = *(const s8v*)(kb0 + SWB(kr0, sl * 32 + hi * 16));
                s8v kf1 = *(const s8v*)(kb1 + SWB(kr1, sl * 32 + hi * 16));
                sc[0] = __builtin_amdgcn_mfma_f32_32x32x16_bf16(kf0, qf[sl], sc[0], 0, 0, 0);
                sc[1] = __builtin_amdgcn_mfma_f32_32x32x16_bf16(kf1, qf[sl], sc[1], 0, 0, 0);
            }
            __builtin_amdgcn_s_setprio(0);
        }

        // ---- online softmax max (log2 domain), tree reduction ----
        float m8[8];
#pragma unroll
        for (int e = 0; e < 8; ++e)
            m8[e] = fmaxf(fmaxf(sc[0][e], sc[0][e + 8]), fmaxf(sc[1][e], sc[1][e + 8]));
        float pm = fmaxf(fmaxf(fmaxf(m8[0], m8[4]), fmaxf(m8[1], m8[5])),
                         fmaxf(fmaxf(m8[2], m8[6]), fmaxf(m8[3], m8[7])));
        pm = fmaxf(pm, __shfl_xor(pm, 32, 64));
        if (__any(pm > m2 + 8.0f)) {          // defer-max (T13)
            float m2n = fmaxf(m2, pm);
            float fr = __builtin_amdgcn_exp2f(m2 - m2n);
            sumacc[0] *= fr;                  // only [0] is ever read
#pragma unroll
            for (int dt = 0; dt < 2; ++dt)
#pragma unroll
                for (int e = 0; e < 16; ++e) oacc[dt][e] *= fr;
            m2 = m2n;
        }
#pragma unroll
        for (int c = 0; c < 2; ++c)
#pragma unroll
            for (int e = 0; e < 16; ++e)
                sc[c][e] = __builtin_amdgcn_exp2f(sc[c][e] - m2);

        // ---- P->bf16 frags; PV + denominator both on the MFMA pipe ----
#pragma unroll
        for (int c = 0; c < 2; ++c) {
#pragma unroll
            for (int ks = 0; ks < 2; ++ks) {
                const int b0 = ks * 8;
                unsigned x0 = cvtpk(sc[c][b0 + 0], sc[c][b0 + 1]);
                unsigned y0 = cvtpk(sc[c][b0 + 4], sc[c][b0 + 5]);
                unsigned x1 = cvtpk(sc[c][b0 + 2], sc[c][b0 + 3]);
                unsigned y1 = cvtpk(sc[c][b0 + 6], sc[c][b0 + 7]);
                plswap(x0, y0);
                plswap(x1, y1);
                union { unsigned u[4]; s8v s; } pf;
                pf.u[0] = x0; pf.u[1] = x1; pf.u[2] = y0; pf.u[3] = y1;
                __builtin_amdgcn_s_setprio(1);
#pragma unroll
                for (int dt = 0; dt < 2; ++dt) {
                    const int vrow = dt * 32 + q5;
                    s8v vf = *(const s8v*)(VlB + vrow * 128 +
                                           SWB(vrow, c * 64 + ks * 32 + hi * 16));
                    oacc[dt] = __builtin_amdgcn_mfma_f32_32x32x16_bf16(vf, pf.s, oacc[dt], 0, 0, 0);
                }
                sumacc = __builtin_amdgcn_mfma_f32_32x32x16_bf16(ones8, pf.s, sumacc, 0, 0, 0);
                __builtin_amdgcn_s_setprio(0);
            }
        }

        if (pre) {   // write-late into the other buffer
            char* Kn = (char*)Kl[cur ^ 1];
            char* Vn = (char*)Vl[cur ^ 1];
            *(s8v*)(Kn + w0) = g0; *(s8v*)(Kn + w1) = g1;
            *(s8v*)(Vn + w0) = g2; *(s8v*)(Vn + w1) = g3;
        }
        __syncthreads();             // ONE barrier per tile
        cur ^= 1;
    }

    // ---- epilogue: sumacc[0] is the complete per-q denominator ----
    float ls = sumacc[0];
    float inv = 1.0f / ls;
    short* Pp = (split ? P1 : P0) + ((size_t)bh * S_LEN + qrow) * 64;
#pragma unroll
    for (int dt = 0; dt < 2; ++dt)
#pragma unroll
        for (int g = 0; g < 4; ++g) {
            s4v o4;
#pragma unroll
            for (int jj = 0; jj < 4; ++jj) o4[jj] = f2b(oacc[dt][g * 4 + jj] * inv);
            const int d0 = dt * 32 + g * 8 + hi * 4;
            *(s4v*)&Pp[d0] = o4;
        }
    if (hi == 0) {
        float2 ml; ml.x = m2; ml.y = ls;
        ML[(size_t)split * (32 * S_LEN) + bh * S_LEN + qrow] = ml;
    }
}

// ---------------- combine 2 splits -> Obf [b][s][h*64+d] -----------------------
__global__ __launch_bounds__(256) void attn_combine(
    const short* __restrict__ P0, const short* __restrict__ P1,
    const float2* __restrict__ ML, short* __restrict__ Obf)
{
    int idx = blockIdx.x * 256 + threadIdx.x;   // 524288
    int row = idx >> 3;                         // bh*2048 + s
    int d0 = (idx & 7) * 8;
    float2 a = ML[row];
    float2 b = ML[32 * S_LEN + row];
    float m = fmaxf(a.x, b.x);
    float w0 = a.y * exp2f(a.x - m);
    float w1 = b.y * exp2f(b.x - m);
    float inv = 1.0f / (w0 + w1);
    w0 *= inv; w1 *= inv;
    s8v v0 = *(const s8v*)&P0[(size_t)row * 64 + d0];
    s8v v1 = *(const s8v*)&P1[(size_t)row * 64 + d0];
    s8v o;
#pragma unroll
    for (int e = 0; e < 8; ++e) o[e] = f2b(w0 * b2f(v0[e]) + w1 * b2f(v1[e]));
    int bh = row >> 11, s = row & 2047;
    int b_ = bh >> 4, h = bh & 15;
    *(s8v*)&Obf[((size_t)(b_ * S_LEN + s)) * HID_ + h * 64 + d0] = o;
}

// ---------------- launch ----------------
extern "C" void kernel_launch(void* const* d_in, const int* in_sizes, int n_in,
                              void* d_out, int out_size, void* d_ws, size_t ws_size,
                              hipStream_t stream)
{
    const float* X  = (const float*)d_in[0];
    const float* Wq = (const float*)d_in[1];
    const float* bq = (const float*)d_in[2];
    const float* Wk = (const float*)d_in[3];
    const float* bk = (const float*)d_in[4];
    const float* Wv = (const float*)d_in[5];
    const float* bv = (const float*)d_in[6];
    const float* Wo = (const float*)d_in[7];
    const float* bo = (const float*)d_in[8];
    float* out = (float*)d_out;

    char* ws = (char*)d_ws;
    short*  Xb   = (short*) (ws);                      // 8 MB
    short*  Wcat = (short*) (ws + ( 8u << 20));        // 6 MB
    short*  Wob  = (short*) (ws + (14u << 20));        // 2 MB
    float2* rtab = (float2*)(ws + (16u << 20));        // 512 KB
    short*  Qbh  = (short*) (ws + (17u << 20));        // 8 MB
    short*  Kbh  = (short*) (ws + (25u << 20));
    short*  Vbh  = (short*) (ws + (33u << 20));        // 8 MB (V^T)
    short*  Obf  = (short*) (ws + (41u << 20));        // 8 MB
    short*  P0   = (short*) (ws);                      // over Xb (dead after gemm_qkv)
    short*  P1   = (short*) d_out;                     // rewritten by gemm_o
    float2* ML   = (float2*)((char*)d_out + (8u << 20));

    prep_kernel<<<4352, 256, 0, stream>>>(X, Wq, Wk, Wv, Wo, Xb, Wcat, Wob, rtab);
    gemm_qkv<<<768, 256, 0, stream>>>(Xb, Wcat, bq, bk, bv, Qbh, Kbh, Vbh, rtab);
    attn_split<<<1024, 256, 0, stream>>>(Qbh, Kbh, Vbh, P0, P1, ML);
    attn_combine<<<2048, 256, 0, stream>>>(P0, P1, ML, Obf);
    gemm_o<<<512, 256, 0, stream>>>(Obf, Wob, bo, out);
}

// Round 16
// 130.791 us; speedup vs baseline: 1.2396x; 1.2396x over previous
//
#include <hip/hip_runtime.h>
#include <cstdint>
#include <cstddef>

#define S_LEN 2048
#define NHEAD 16
#define HDIM  64
#define HID_  1024

typedef short s8v  __attribute__((ext_vector_type(8)));
typedef short s4v  __attribute__((ext_vector_type(4)));
typedef float f4v  __attribute__((ext_vector_type(4)));
typedef float f16v __attribute__((ext_vector_type(16)));

__device__ __forceinline__ short f2b(float x) {
    union { float f; unsigned u; } a; a.f = x;
    unsigned r = a.u + 0x7fffu + ((a.u >> 16) & 1u);
    return (short)(r >> 16);
}
__device__ __forceinline__ float b2f(short x) {
    union { unsigned u; float f; } a; a.u = ((unsigned)(unsigned short)x) << 16;
    return a.f;
}

__device__ __forceinline__ unsigned cvtpk(float a, float b) {
    unsigned r;
    asm("v_cvt_pk_bf16_f32 %0, %1, %2" : "=v"(r) : "v"(a), "v"(b));
    return r;
}
__device__ __forceinline__ void plswap(unsigned& a, unsigned& b) {
    asm("v_permlane32_swap_b32 %0, %1" : "+v"(a), "+v"(b));
}

// ---------------- merged prep: X->bf16, weights->bf16, RoPE table --------------
__global__ __launch_bounds__(256) void prep_kernel(
    const float* __restrict__ X,
    const float* __restrict__ Wq, const float* __restrict__ Wk,
    const float* __restrict__ Wv, const float* __restrict__ Wo,
    short* __restrict__ Xb, short* __restrict__ Wcat, short* __restrict__ Wob,
    float2* __restrict__ rtab)
{
    const int bid = blockIdx.x;
    if (bid < 4096) {
        const float* src;
        short* dst;
        int i;
        if (bid < 2048) {
            src = X; dst = Xb; i = (bid * 256 + threadIdx.x) * 2;
        } else {
            int w = (bid - 2048) >> 9;             // 0..3
            src = (w == 0) ? Wq : (w == 1) ? Wk : (w == 2) ? Wv : Wo;
            dst = (w < 3) ? (Wcat + (size_t)w * 1048576) : Wob;
            i = (((bid - 2048) & 511) * 256 + threadIdx.x) * 2;
        }
        float4 v0 = reinterpret_cast<const float4*>(src)[i];
        float4 v1 = reinterpret_cast<const float4*>(src)[i + 1];
        s8v o;
        o[0] = f2b(v0.x); o[1] = f2b(v0.y); o[2] = f2b(v0.z); o[3] = f2b(v0.w);
        o[4] = f2b(v1.x); o[5] = f2b(v1.y); o[6] = f2b(v1.z); o[7] = f2b(v1.w);
        *reinterpret_cast<s8v*>(&dst[i * 4]) = o;
    } else {
        int idx = (bid - 4096) * 256 + threadIdx.x;   // 65536
        int s = idx >> 5, j = idx & 31;
        float inv = exp2f(-0.5f * (float)j);          // 65536^(-2j/64)
        float ang = (float)s * inv;
        float2 cs; cs.x = cosf(ang); cs.y = sinf(ang);
        rtab[idx] = cs;
    }
}

// ---------------- fused QKV GEMM: 2x16KB buffers, reg-staged, ONE barrier/step -
__global__ __launch_bounds__(256, 4) void gemm_qkv(
    const short* __restrict__ A, const short* __restrict__ Bw,
    const float* __restrict__ bq, const float* __restrict__ bk,
    const float* __restrict__ bv,
    short* __restrict__ Qo, short* __restrict__ Ko, short* __restrict__ Vo,
    const float2* __restrict__ rtab)
{
    __shared__ short Asl[2][4096];   // 128x32 bf16 (8KB) x2
    __shared__ short Bsl[2][4096];
    const int t = threadIdx.x;
    const int lane = t & 63;
    const int l15 = lane & 15, l4 = lane >> 4;
    const int wid = t >> 6;
    const int blk = blockIdx.x;
    const int x = blk & 7, j = blk >> 3;       // j in [0,96)
    const int tn = (x * 3 + j % 3) * 128;
    const int tm = (j / 3) * 128;
    const int K = 1024;
    const int wrow = (wid >> 1) * 64, wcol = (wid & 1) * 64;

    f4v acc[4][4];
#pragma unroll
    for (int i = 0; i < 4; ++i)
#pragma unroll
        for (int jj = 0; jj < 4; ++jj) acc[i][jj] = (f4v){0.f, 0.f, 0.f, 0.f};

    const int r0 = t >> 2;            // staging row within 64-row half
    const int c0 = (t & 3) * 8;       // k-col (8 bf16)

    const short* Ap0 = A  + (size_t)(tm + r0)      * K + c0;
    const short* Ap1 = A  + (size_t)(tm + 64 + r0) * K + c0;
    const short* Bp0 = Bw + (size_t)(tn + r0)      * K + c0;
    const short* Bp1 = Bw + (size_t)(tn + 64 + r0) * K + c0;
    const int wofs = t * 8;

    {   // prologue: tile 0 -> buf 0
        s8v ga0 = *(const s8v*)(Ap0);
        s8v ga1 = *(const s8v*)(Ap1);
        s8v gb0 = *(const s8v*)(Bp0);
        s8v gb1 = *(const s8v*)(Bp1);
        *(s8v*)&Asl[0][wofs] = ga0; *(s8v*)&Asl[0][2048 + wofs] = ga1;
        *(s8v*)&Bsl[0][wofs] = gb0; *(s8v*)&Bsl[0][2048 + wofs] = gb1;
    }
    __syncthreads();

    int cur = 0;
    for (int kt = 0; kt < 32; ++kt) {
        s8v ga0, ga1, gb0, gb1;
        const bool pre = (kt < 31);
        if (pre) {   // T14 issue-early
            const int k0 = (kt + 1) << 5;
            ga0 = *(const s8v*)(Ap0 + k0);
            ga1 = *(const s8v*)(Ap1 + k0);
            gb0 = *(const s8v*)(Bp0 + k0);
            gb1 = *(const s8v*)(Bp1 + k0);
        }
        s8v af[4], bf[4];
#pragma unroll
        for (int i = 0; i < 4; ++i) {
            af[i] = *(const s8v*)&Asl[cur][(wrow + i * 16 + l15) * 32 + 8 * l4];
            bf[i] = *(const s8v*)&Bsl[cur][(wcol + i * 16 + l15) * 32 + 8 * l4];
        }
#pragma unroll
        for (int i = 0; i < 4; ++i)
#pragma unroll
            for (int jj = 0; jj < 4; ++jj)
                acc[i][jj] = __builtin_amdgcn_mfma_f32_16x16x32_bf16(af[i], bf[jj], acc[i][jj], 0, 0, 0);
        if (pre) {   // write-late into the OTHER buffer
            *(s8v*)&Asl[cur ^ 1][wofs] = ga0; *(s8v*)&Asl[cur ^ 1][2048 + wofs] = ga1;
            *(s8v*)&Bsl[cur ^ 1][wofs] = gb0; *(s8v*)&Bsl[cur ^ 1][2048 + wofs] = gb1;
        }
        __syncthreads();             // ONE barrier per K-step
        cur ^= 1;
    }

    const int mode = tn >> 10;                         // 0=Q 1=K 2=V
    const float* bias = (mode == 0) ? bq : (mode == 1) ? bk : bv;
    short* outb = (mode == 0) ? Qo : (mode == 1) ? Ko : Vo;

    if (mode == 2) {   // V: write transposed [bh][d][s]
#pragma unroll
        for (int i = 0; i < 4; ++i) {
            int rowb = tm + wrow + i * 16 + l4 * 4;
            int b_ = rowb >> 11, s0 = rowb & 2047;
#pragma unroll
            for (int jj = 0; jj < 4; ++jj) {
                int col = tn + wcol + jj * 16 + l15;
                int cm = col & 1023;
                float bvv = bias[cm];
                int h = cm >> 6, d = col & 63;
                s4v o4;
#pragma unroll
                for (int r = 0; r < 4; ++r) o4[r] = f2b(acc[i][jj][r] + bvv);
                *(s4v*)&outb[((size_t)((b_ * NHEAD + h) * 64 + d)) * S_LEN + s0] = o4;
            }
        }
    } else {           // Q or K: RoPE. Wave spans exactly one head (64 cols).
        int h = ((tn & 1023) + wcol) >> 6;
        const float osc = (mode == 0) ? 0.180336880111f : 1.0f;  // 1/8 * log2(e)
#pragma unroll
        for (int i = 0; i < 4; ++i) {
#pragma unroll
            for (int r = 0; r < 4; ++r) {
                int row = tm + wrow + i * 16 + l4 * 4 + r;
                int b_ = row >> 11, s = row & 2047;
                float2 cs0 = rtab[(s << 5) + l15];
                float2 cs1 = rtab[(s << 5) + 16 + l15];
#pragma unroll
                for (int jj = 0; jj < 4; ++jj) {
                    int col = tn + wcol + jj * 16 + l15;
                    int cm = col & 1023;
                    int d = col & 63;
                    float v  = acc[i][jj][r]     + bias[cm];
                    float vp = acc[i][jj ^ 2][r] + bias[cm ^ 32];
                    float2 cs = (jj & 1) ? cs1 : cs0;
                    float res = (d < 32) ? (v * cs.x - vp * cs.y)
                                         : (v * cs.x + vp * cs.y);
                    outb[(((size_t)(b_ * NHEAD + h) * S_LEN + s) << 6) + d] = f2b(res * osc);
                }
            }
        }
    }
}

// ---------------- O-proj GEMM: BM=64, 2-buf reg-staged, ONE barrier/step -------
__global__ __launch_bounds__(256, 4) void gemm_o(
    const short* __restrict__ A, const short* __restrict__ Bw,
    const float* __restrict__ bias, float* __restrict__ outf)
{
    __shared__ short Asl[2][2048];   // 64x32 (4KB) x2
    __shared__ short Bsl[2][4096];   // 128x32 (8KB) x2
    const int t = threadIdx.x;
    const int lane = t & 63;
    const int l15 = lane & 15, l4 = lane >> 4;
    const int wid = t >> 6;
    const int blk = blockIdx.x;                 // 512
    const int tn = (blk & 7) * 128;
    const int tm = (blk >> 3) * 64;
    const int K = 1024, N = 1024;
    const int wrow = (wid >> 1) * 32, wcol = (wid & 1) * 64;

    f4v acc[2][4];
#pragma unroll
    for (int i = 0; i < 2; ++i)
#pragma unroll
        for (int jj = 0; jj < 4; ++jj) acc[i][jj] = (f4v){0.f, 0.f, 0.f, 0.f};

    const int r0 = t >> 2;
    const int c0 = (t & 3) * 8;
    const short* Ap0 = A  + (size_t)(tm + r0)      * K + c0;
    const short* Bp0 = Bw + (size_t)(tn + r0)      * K + c0;
    const short* Bp1 = Bw + (size_t)(tn + 64 + r0) * K + c0;
    const int wofs = t * 8;

    {   // prologue
        s8v ga0 = *(const s8v*)(Ap0);
        s8v gb0 = *(const s8v*)(Bp0);
        s8v gb1 = *(const s8v*)(Bp1);
        *(s8v*)&Asl[0][wofs] = ga0;
        *(s8v*)&Bsl[0][wofs] = gb0; *(s8v*)&Bsl[0][2048 + wofs] = gb1;
    }
    __syncthreads();

    int cur = 0;
    for (int kt = 0; kt < 32; ++kt) {
        s8v ga0, gb0, gb1;
        const bool pre = (kt < 31);
        if (pre) {
            const int k0 = (kt + 1) << 5;
            ga0 = *(const s8v*)(Ap0 + k0);
            gb0 = *(const s8v*)(Bp0 + k0);
            gb1 = *(const s8v*)(Bp1 + k0);
        }
        s8v af[2], bf[4];
#pragma unroll
        for (int i = 0; i < 2; ++i)
            af[i] = *(const s8v*)&Asl[cur][(wrow + i * 16 + l15) * 32 + 8 * l4];
#pragma unroll
        for (int jj = 0; jj < 4; ++jj)
            bf[jj] = *(const s8v*)&Bsl[cur][(wcol + jj * 16 + l15) * 32 + 8 * l4];
#pragma unroll
        for (int i = 0; i < 2; ++i)
#pragma unroll
            for (int jj = 0; jj < 4; ++jj)
                acc[i][jj] = __builtin_amdgcn_mfma_f32_16x16x32_bf16(af[i], bf[jj], acc[i][jj], 0, 0, 0);
        if (pre) {
            *(s8v*)&Asl[cur ^ 1][wofs] = ga0;
            *(s8v*)&Bsl[cur ^ 1][wofs] = gb0; *(s8v*)&Bsl[cur ^ 1][2048 + wofs] = gb1;
        }
        __syncthreads();             // ONE barrier per K-step
        cur ^= 1;
    }

#pragma unroll
    for (int i = 0; i < 2; ++i) {
        int rowb = tm + wrow + i * 16 + l4 * 4;
#pragma unroll
        for (int jj = 0; jj < 4; ++jj) {
            int col = tn + wcol + jj * 16 + l15;
            float bv = bias[col];
#pragma unroll
            for (int r = 0; r < 4; ++r)
                outf[(size_t)(rowb + r) * N + col] = acc[i][jj][r] + bv;
        }
    }
}

// ---------------- attention, split-KV, 2x16KB dbuf, ONE barrier/tile -----------
// (R14 winner: VALU tree-sum softmax; sumacc-MFMA variant regressed via spills.)
#define SWB(row, bofs) ((bofs) ^ (((row) & 7) << 4))

__global__ __launch_bounds__(256, 4) void attn_split(
    const short* __restrict__ Q, const short* __restrict__ K,
    const short* __restrict__ Vt,
    short* __restrict__ P0, short* __restrict__ P1, float2* __restrict__ ML)
{
    __shared__ short Kl[2][4096];   // [key][d] 64x64, swizzled rows (8KB each)
    __shared__ short Vl[2][4096];   // [d][key] 64x64, swizzled rows

    const int t = threadIdx.x, lane = t & 63;
    const int wid = t >> 6;
    const int q5 = lane & 31, hi = lane >> 5;

    const int blk = blockIdx.x;
    const int x = blk & 7, j = blk >> 3;       // j in [0,128)
    const int bh = x * 4 + (j & 3);
    const int rest = j >> 2;                   // 0..31
    const int qb = rest & 15, split = rest >> 4;
    const int kt0 = split * 16;

    const short* Qb = Q + (size_t)bh * S_LEN * 64;
    const char*  Kb = (const char*)(K  + (size_t)bh * S_LEN * 64);
    const char*  Vb = (const char*)(Vt + (size_t)bh * S_LEN * 64);
    const int qrow = qb * 128 + wid * 32 + q5;

    s8v qf[4];
#pragma unroll
    for (int sl = 0; sl < 4; ++sl)
        qf[sl] = *(const s8v*)&Qb[(size_t)qrow * 64 + sl * 16 + hi * 8];

    f16v oacc[2];
#pragma unroll
    for (int dt = 0; dt < 2; ++dt)
#pragma unroll
        for (int e = 0; e < 16; ++e) oacc[dt][e] = 0.f;
    float m2 = -1e30f, lsum = 0.f;

    const int skey  = t >> 3;                  // 0..31
    const int sboff = (t & 7) * 16;
    const int sw    = SWB(skey, sboff);
    const size_t kgoff = (size_t)skey * 128  + sboff;
    const size_t vgoff = (size_t)skey * 4096 + sboff;
    const int w0 = skey * 128 + sw;
    const int w1 = w0 + 32 * 128;

    {   // prologue: tile kt0 -> buf 0
        const size_t kbB = (size_t)kt0 * 64 * 128;
        const size_t vbB = (size_t)kt0 * 64 * 2;
        s8v g0 = *(const s8v*)(Kb + kbB + kgoff);
        s8v g1 = *(const s8v*)(Kb + kbB + kgoff + 32 * 128);
        s8v g2 = *(const s8v*)(Vb + vbB + vgoff);
        s8v g3 = *(const s8v*)(Vb + vbB + vgoff + 32 * 4096);
        *(s8v*)((char*)Kl[0] + w0) = g0; *(s8v*)((char*)Kl[0] + w1) = g1;
        *(s8v*)((char*)Vl[0] + w0) = g2; *(s8v*)((char*)Vl[0] + w1) = g3;
    }
    __syncthreads();

    int cur = 0;
    for (int kt = kt0; kt < kt0 + 16; ++kt) {
        s8v g0, g1, g2, g3;
        const bool pre = (kt < kt0 + 15);
        if (pre) {   // issue-early global loads for tile kt+1
            const size_t kbB = (size_t)(kt + 1) * 64 * 128;
            const size_t vbB = (size_t)(kt + 1) * 64 * 2;
            g0 = *(const s8v*)(Kb + kbB + kgoff);
            g1 = *(const s8v*)(Kb + kbB + kgoff + 32 * 128);
            g2 = *(const s8v*)(Vb + vbB + vgoff);
            g3 = *(const s8v*)(Vb + vbB + vgoff + 32 * 4096);
        }
        const char* KlB = (const char*)Kl[cur];
        const char* VlB = (const char*)Vl[cur];

        // ---- QK^T (swapped), interleaved c-chains ----
        f16v sc[2];
#pragma unroll
        for (int e = 0; e < 16; ++e) { sc[0][e] = 0.f; sc[1][e] = 0.f; }
        {
            const int kr0 = q5, kr1 = 32 + q5;
            const char* kb0 = KlB + kr0 * 128;
            const char* kb1 = KlB + kr1 * 128;
            __builtin_amdgcn_s_setprio(1);
#pragma unroll
            for (int sl = 0; sl < 4; ++sl) {
                s8v kf0 = *(const s8v*)(kb0 + SWB(kr0, sl * 32 + hi * 16));
                s8v kf1 = *(const s8v*)(kb1 + SWB(kr1, sl * 32 + hi * 16));
                sc[0] = __builtin_amdgcn_mfma_f32_32x32x16_bf16(kf0, qf[sl], sc[0], 0, 0, 0);
                sc[1] = __builtin_amdgcn_mfma_f32_32x32x16_bf16(kf1, qf[sl], sc[1], 0, 0, 0);
            }
            __builtin_amdgcn_s_setprio(0);
        }

        // ---- online softmax (log2 domain), tree reductions ----
        float m8[8];
#pragma unroll
        for (int e = 0; e < 8; ++e)
            m8[e] = fmaxf(fmaxf(sc[0][e], sc[0][e + 8]), fmaxf(sc[1][e], sc[1][e + 8]));
        float pm = fmaxf(fmaxf(fmaxf(m8[0], m8[4]), fmaxf(m8[1], m8[5])),
                         fmaxf(fmaxf(m8[2], m8[6]), fmaxf(m8[3], m8[7])));
        pm = fmaxf(pm, __shfl_xor(pm, 32, 64));
        if (__any(pm > m2 + 8.0f)) {          // defer-max (T13)
            float m2n = fmaxf(m2, pm);
            float fr = __builtin_amdgcn_exp2f(m2 - m2n);
            lsum *= fr;
#pragma unroll
            for (int dt = 0; dt < 2; ++dt)
#pragma unroll
                for (int e = 0; e < 16; ++e) oacc[dt][e] *= fr;
            m2 = m2n;
        }
#pragma unroll
        for (int c = 0; c < 2; ++c)
#pragma unroll
            for (int e = 0; e < 16; ++e)
                sc[c][e] = __builtin_amdgcn_exp2f(sc[c][e] - m2);
        float sum8[8];
#pragma unroll
        for (int e = 0; e < 8; ++e)
            sum8[e] = (sc[0][e] + sc[0][e + 8]) + (sc[1][e] + sc[1][e + 8]);
        lsum += ((sum8[0] + sum8[4]) + (sum8[1] + sum8[5])) +
                ((sum8[2] + sum8[6]) + (sum8[3] + sum8[7]));

        // ---- P->bf16 frags (cvt_pk + permlane32_swap) and PV (swapped) ----
#pragma unroll
        for (int c = 0; c < 2; ++c) {
#pragma unroll
            for (int ks = 0; ks < 2; ++ks) {
                const int b0 = ks * 8;
                unsigned x0 = cvtpk(sc[c][b0 + 0], sc[c][b0 + 1]);
                unsigned y0 = cvtpk(sc[c][b0 + 4], sc[c][b0 + 5]);
                unsigned x1 = cvtpk(sc[c][b0 + 2], sc[c][b0 + 3]);
                unsigned y1 = cvtpk(sc[c][b0 + 6], sc[c][b0 + 7]);
                plswap(x0, y0);
                plswap(x1, y1);
                union { unsigned u[4]; s8v s; } pf;
                pf.u[0] = x0; pf.u[1] = x1; pf.u[2] = y0; pf.u[3] = y1;
                __builtin_amdgcn_s_setprio(1);
#pragma unroll
                for (int dt = 0; dt < 2; ++dt) {
                    const int vrow = dt * 32 + q5;
                    s8v vf = *(const s8v*)(VlB + vrow * 128 +
                                           SWB(vrow, c * 64 + ks * 32 + hi * 16));
                    oacc[dt] = __builtin_amdgcn_mfma_f32_32x32x16_bf16(vf, pf.s, oacc[dt], 0, 0, 0);
                }
                __builtin_amdgcn_s_setprio(0);
            }
        }

        if (pre) {   // write-late into the other buffer
            char* Kn = (char*)Kl[cur ^ 1];
            char* Vn = (char*)Vl[cur ^ 1];
            *(s8v*)(Kn + w0) = g0; *(s8v*)(Kn + w1) = g1;
            *(s8v*)(Vn + w0) = g2; *(s8v*)(Vn + w1) = g3;
        }
        __syncthreads();             // ONE barrier per tile
        cur ^= 1;
    }

    // ---- epilogue ----
    float ls = lsum + __shfl_xor(lsum, 32, 64);
    float inv = 1.0f / ls;
    short* Pp = (split ? P1 : P0) + ((size_t)bh * S_LEN + qrow) * 64;
#pragma unroll
    for (int dt = 0; dt < 2; ++dt)
#pragma unroll
        for (int g = 0; g < 4; ++g) {
            s4v o4;
#pragma unroll
            for (int jj = 0; jj < 4; ++jj) o4[jj] = f2b(oacc[dt][g * 4 + jj] * inv);
            const int d0 = dt * 32 + g * 8 + hi * 4;
            *(s4v*)&Pp[d0] = o4;
        }
    if (hi == 0) {
        float2 ml; ml.x = m2; ml.y = ls;
        ML[(size_t)split * (32 * S_LEN) + bh * S_LEN + qrow] = ml;
    }
}

// ---------------- combine 2 splits -> Obf [b][s][h*64+d] -----------------------
__global__ __launch_bounds__(256) void attn_combine(
    const short* __restrict__ P0, const short* __restrict__ P1,
    const float2* __restrict__ ML, short* __restrict__ Obf)
{
    int idx = blockIdx.x * 256 + threadIdx.x;   // 524288
    int row = idx >> 3;                         // bh*2048 + s
    int d0 = (idx & 7) * 8;
    float2 a = ML[row];
    float2 b = ML[32 * S_LEN + row];
    float m = fmaxf(a.x, b.x);
    float w0 = a.y * exp2f(a.x - m);
    float w1 = b.y * exp2f(b.x - m);
    float inv = 1.0f / (w0 + w1);
    w0 *= inv; w1 *= inv;
    s8v v0 = *(const s8v*)&P0[(size_t)row * 64 + d0];
    s8v v1 = *(const s8v*)&P1[(size_t)row * 64 + d0];
    s8v o;
#pragma unroll
    for (int e = 0; e < 8; ++e) o[e] = f2b(w0 * b2f(v0[e]) + w1 * b2f(v1[e]));
    int bh = row >> 11, s = row & 2047;
    int b_ = bh >> 4, h = bh & 15;
    *(s8v*)&Obf[((size_t)(b_ * S_LEN + s)) * HID_ + h * 64 + d0] = o;
}

// ---------------- launch ----------------
extern "C" void kernel_launch(void* const* d_in, const int* in_sizes, int n_in,
                              void* d_out, int out_size, void* d_ws, size_t ws_size,
                              hipStream_t stream)
{
    const float* X  = (const float*)d_in[0];
    const float* Wq = (const float*)d_in[1];
    const float* bq = (const float*)d_in[2];
    const float* Wk = (const float*)d_in[3];
    const float* bk = (const float*)d_in[4];
    const float* Wv = (const float*)d_in[5];
    const float* bv = (const float*)d_in[6];
    const float* Wo = (const float*)d_in[7];
    const float* bo = (const float*)d_in[8];
    float* out = (float*)d_out;

    char* ws = (char*)d_ws;
    short*  Xb   = (short*) (ws);                      // 8 MB
    short*  Wcat = (short*) (ws + ( 8u << 20));        // 6 MB
    short*  Wob  = (short*) (ws + (14u << 20));        // 2 MB
    float2* rtab = (float2*)(ws + (16u << 20));        // 512 KB
    short*  Qbh  = (short*) (ws + (17u << 20));        // 8 MB
    short*  Kbh  = (short*) (ws + (25u << 20));
    short*  Vbh  = (short*) (ws + (33u << 20));        // 8 MB (V^T)
    short*  Obf  = (short*) (ws + (41u << 20));        // 8 MB
    short*  P0   = (short*) (ws);                      // over Xb (dead after gemm_qkv)
    short*  P1   = (short*) d_out;                     // rewritten by gemm_o
    float2* ML   = (float2*)((char*)d_out + (8u << 20));

    prep_kernel<<<4352, 256, 0, stream>>>(X, Wq, Wk, Wv, Wo, Xb, Wcat, Wob, rtab);
    gemm_qkv<<<768, 256, 0, stream>>>(Xb, Wcat, bq, bk, bv, Qbh, Kbh, Vbh, rtab);
    attn_split<<<1024, 256, 0, stream>>>(Qbh, Kbh, Vbh, P0, P1, ML);
    attn_combine<<<2048, 256, 0, stream>>>(P0, P1, ML, Obf);
    gemm_o<<<512, 256, 0, stream>>>(Obf, Wob, bo, out);
}